// Round 1
// baseline (331.598 us; speedup 1.0000x reference)
//
#include <hip/hip_runtime.h>
#include <hip/hip_cooperative_groups.h>

namespace cg = cooperative_groups;

#define TSEQ 1024
#define HIDV 64
#define NHEADS 16      // N*H = 2*8
#define LCH 64         // chunk length
#define NCH 16         // TSEQ/LCH
#define EMBED 512
#define CTX_FLOATS (NHEADS * TSEQ * HIDV)           // 1048576
#define EPSV 1e-6f
#define PIH 1.5707963267948966f

typedef short bf16x8 __attribute__((ext_vector_type(8)));
typedef float f32x4 __attribute__((ext_vector_type(4)));

__device__ __forceinline__ float relu_f(float x) { return fmaxf(x, 0.0f); }
__device__ __forceinline__ ushort f2bf(float f) {
    uint u = __float_as_uint(f);
    u += 0x7FFF + ((u >> 16) & 1);          // RNE
    return (ushort)(u >> 16);
}
__device__ __forceinline__ float bf2f(ushort h) { return __uint_as_float(((uint)h) << 16); }
__device__ __forceinline__ uint pk2(float a, float b) {
    return (uint)f2bf(a) | ((uint)f2bf(b) << 16);
}

// ---------------------------------------------------------------------------
// Single fused cooperative kernel: 512 blocks x 256 threads, 2 blocks/CU.
// LDS union (62976 B):
//   region1 kw  [64][136] ushort  17408 B   (phase A writes, phase B reads)
//   region2 vT  [32][88]  ushort   5632 B   (phase A writes, A+B read)
//   region3               22528 B:  A: kwT [128][88]
//                                   B: Pt[32][136] | Am[64][72] | psum[128]f | denA[64]f | denI[64]f
//   region4               17408 B:  A/B: qw [64][136]; B-epilogue: Orep[64][40]; C: Ab[32][72]+Bb[64][72]
// ---------------------------------------------------------------------------
#define LDS_BYTES 62976
#define OFF_KW   0
#define OFF_VT   17408
#define OFF_R3   23040
#define OFF_R4   45568
#define OFF_PT   (OFF_R3 + 0)
#define OFF_AM   (OFF_R3 + 8704)
#define OFF_PSUM (OFF_R3 + 17920)
#define OFF_DENA (OFF_R3 + 18432)
#define OFF_DENI (OFF_R3 + 18688)

__global__ __launch_bounds__(256, 2) void kFused(
    const float* __restrict__ Q, const float* __restrict__ K,
    const float* __restrict__ V, const float* __restrict__ W,
    const float* __restrict__ bias,
    ushort* __restrict__ S16, float* __restrict__ ksumws,
    ushort* __restrict__ attn216, ushort* __restrict__ W16,
    float* __restrict__ out, float4* __restrict__ probs4)
{
    __shared__ __align__(16) char smem[LDS_BYTES];
    ushort* kw = (ushort*)(smem + OFF_KW);
    ushort* vT = (ushort*)(smem + OFF_VT);
    ushort* qw = (ushort*)(smem + OFF_R4);

    const int bid = blockIdx.x;
    const int tid = threadIdx.x;
    const int w = tid >> 6, lane = tid & 63;
    const int quad = lane >> 4, l15 = lane & 15;
    const int pair = bid >> 1, mh = bid & 1, m0b = mh * 32;
    const int b = pair >> 4, c = pair & 15;
    const int l0 = c * LCH;

    cg::grid_group grid = cg::this_grid();

    // =========================== Phase A ===================================
    {   // probs zero slice 0 (nontemporal: never re-read, keep out of L2)
        f32x4 z = {0.f, 0.f, 0.f, 0.f};
        size_t base = (size_t)bid * 2560 + tid;
        #pragma unroll
        for (int s = 0; s < 10; ++s)
            __builtin_nontemporal_store(z, (f32x4*)&probs4[base + s * 256]);
    }
    {   // W (512x512 fp32) -> bf16
        int g = bid * 128 + (tid & 127);
        if (tid < 128) {
            float4 w4 = *(const float4*)(W + (size_t)g * 4);
            *(uint2*)(W16 + (size_t)g * 4) = make_uint2(pk2(w4.x, w4.y), pk2(w4.z, w4.w));
        }
    }
    {
        ushort* kwT = (ushort*)(smem + OFF_R3);
        #pragma unroll
        for (int s = 0; s < 4; ++s) {
            int e = tid + s * 256;               // f4 over 64x64
            int i = e >> 4, d = (e & 15) * 4;
            float si, ci;
            __sincosf(PIH * (float)(l0 + i + 1) * (1.0f / 1024.0f), &si, &ci);
            float4 k4 = *(const float4*)(K + (size_t)(b * TSEQ + l0 + i) * HIDV + d);
            float kv[4] = {relu_f(k4.x), relu_f(k4.y), relu_f(k4.z), relu_f(k4.w)};
            #pragma unroll
            for (int j = 0; j < 4; ++j) {
                kwT[(d + j) * 88 + i] = f2bf(si * kv[j]);
                kwT[(d + 64 + j) * 88 + i] = f2bf(ci * kv[j]);
            }
            *(uint2*)(kw + i * 136 + d) = make_uint2(pk2(si * kv[0], si * kv[1]), pk2(si * kv[2], si * kv[3]));
            *(uint2*)(kw + i * 136 + 64 + d) = make_uint2(pk2(ci * kv[0], ci * kv[1]), pk2(ci * kv[2], ci * kv[3]));
            float4 q4 = *(const float4*)(Q + (size_t)(b * TSEQ + l0 + i) * HIDV + d);
            float qv[4] = {relu_f(q4.x), relu_f(q4.y), relu_f(q4.z), relu_f(q4.w)};
            *(uint2*)(qw + i * 136 + d) = make_uint2(pk2(si * qv[0], si * qv[1]), pk2(si * qv[2], si * qv[3]));
            *(uint2*)(qw + i * 136 + 64 + d) = make_uint2(pk2(ci * qv[0], ci * qv[1]), pk2(ci * qv[2], ci * qv[3]));
        }
        #pragma unroll
        for (int s = 0; s < 2; ++s) {
            int e = tid + s * 256;               // f4 over 64 i x 32 m
            int i = e >> 3, mf = (e & 7) * 4;
            float4 v4 = *(const float4*)(V + ((size_t)(l0 + i) * NHEADS + b) * HIDV + m0b + mf);
            vT[(mf + 0) * 88 + i] = f2bf(v4.x);
            vT[(mf + 1) * 88 + i] = f2bf(v4.y);
            vT[(mf + 2) * 88 + i] = f2bf(v4.z);
            vT[(mf + 3) * 88 + i] = f2bf(v4.w);
        }
        __syncthreads();

        // S^T chunk sums: kwT(dd,i) @ vT(m,i)
        bf16x8 bfv[2][2];
        #pragma unroll
        for (int mt = 0; mt < 2; ++mt)
            #pragma unroll
            for (int kk = 0; kk < 2; ++kk)
                bfv[mt][kk] = *(const bf16x8*)(vT + (mt * 16 + l15) * 88 + kk * 32 + quad * 8);

        f32x4 acc[2][2];
        #pragma unroll
        for (int ii = 0; ii < 2; ++ii)
            #pragma unroll
            for (int mt = 0; mt < 2; ++mt) acc[ii][mt] = (f32x4){0.f, 0.f, 0.f, 0.f};
        #pragma unroll
        for (int ii = 0; ii < 2; ++ii) {
            int itv = w + ii * 4;                // dd-tile 0..7
            #pragma unroll
            for (int kk = 0; kk < 2; ++kk) {
                bf16x8 af = *(const bf16x8*)(kwT + (itv * 16 + l15) * 88 + kk * 32 + quad * 8);
                #pragma unroll
                for (int mt = 0; mt < 2; ++mt)
                    acc[ii][mt] = __builtin_amdgcn_mfma_f32_16x16x32_bf16(af, bfv[mt][kk], acc[ii][mt], 0, 0, 0);
            }
        }
        ushort* SpT = S16 + (size_t)pair * 8192;
        #pragma unroll
        for (int ii = 0; ii < 2; ++ii)
            #pragma unroll
            for (int mt = 0; mt < 2; ++mt) {
                int m = m0b + mt * 16 + l15;
                int ddb = (w + ii * 4) * 16 + quad * 4;
                uint2 pk = make_uint2(pk2(acc[ii][mt][0], acc[ii][mt][1]),
                                      pk2(acc[ii][mt][2], acc[ii][mt][3]));
                *(uint2*)(SpT + m * 128 + ddb) = pk;
            }
        if (mh == 0 && tid < 128) {
            float ssum = 0.f;
            #pragma unroll
            for (int ss = 0; ss < 8; ++ss) {
                uint4 u = *(const uint4*)(kwT + tid * 88 + ss * 8);
                ssum += bf2f((ushort)(u.x & 0xffff)) + bf2f((ushort)(u.x >> 16));
                ssum += bf2f((ushort)(u.y & 0xffff)) + bf2f((ushort)(u.y >> 16));
                ssum += bf2f((ushort)(u.z & 0xffff)) + bf2f((ushort)(u.z >> 16));
                ssum += bf2f((ushort)(u.w & 0xffff)) + bf2f((ushort)(u.w >> 16));
            }
            ksumws[(size_t)pair * 128 + tid] = ssum;
        }
    }
    __threadfence();
    grid.sync();    // A -> B: S16/ksumws visible device-wide; kw/qw/vT persist in LDS

    // =========================== Phase B ===================================
    {
        ushort* Pt = (ushort*)(smem + OFF_PT);
        ushort* Am = (ushort*)(smem + OFF_AM);
        float* psum = (float*)(smem + OFF_PSUM);
        float* denA = (float*)(smem + OFF_DENA);
        float* denI = (float*)(smem + OFF_DENI);

        {   // probs zero slice 1
            f32x4 z = {0.f, 0.f, 0.f, 0.f};
            size_t base = 1310720 + (size_t)bid * 2560 + tid;
            #pragma unroll
            for (int s = 0; s < 10; ++s)
                __builtin_nontemporal_store(z, (f32x4*)&probs4[base + s * 256]);
        }

        // inline exclusive prefix: P[ml][dd] = sum_{cp<c} S[b][cp][m0b+ml][dd]
        {
            const int ml = tid >> 3, dd0 = (tid & 7) * 16;
            const ushort* Sb = S16 + ((size_t)b * NCH) * 8192 + (m0b + ml) * 128 + dd0;
            float accp[16];
            #pragma unroll
            for (int u = 0; u < 16; ++u) accp[u] = 0.f;
            for (int cp = 0; cp < c; ++cp) {
                const ushort* Sp = Sb + (size_t)cp * 8192;
                uint4 u0 = *(const uint4*)(Sp);
                uint4 u1 = *(const uint4*)(Sp + 8);
                uint uu[8] = {u0.x, u0.y, u0.z, u0.w, u1.x, u1.y, u1.z, u1.w};
                #pragma unroll
                for (int p = 0; p < 8; ++p) {
                    accp[p * 2 + 0] += bf2f((ushort)(uu[p] & 0xffff));
                    accp[p * 2 + 1] += bf2f((ushort)(uu[p] >> 16));
                }
            }
            uint pkv[8];
            #pragma unroll
            for (int p = 0; p < 8; ++p) pkv[p] = pk2(accp[p * 2], accp[p * 2 + 1]);
            *(uint4*)(Pt + ml * 136 + dd0) = make_uint4(pkv[0], pkv[1], pkv[2], pkv[3]);
            *(uint4*)(Pt + ml * 136 + dd0 + 8) = make_uint4(pkv[4], pkv[5], pkv[6], pkv[7]);
        }
        if (tid < 128) {
            float s = 0.f;
            const float* Kb = ksumws + (size_t)b * NCH * 128 + tid;
            for (int cp = 0; cp < c; ++cp) s += Kb[cp * 128];
            psum[tid] = s;
        }

        // Q fragments: qw still live in LDS from phase A (stable, no sync needed)
        bf16x8 af[4];
        #pragma unroll
        for (int kk = 0; kk < 4; ++kk)
            af[kk] = *(const bf16x8*)(qw + (w * 16 + l15) * 136 + kk * 32 + quad * 8);

        __syncthreads();   // Pt/psum ready; region3 repurposed

        // QK^T (kw persists from phase A)
        f32x4 accA[4];
        #pragma unroll
        for (int jt = 0; jt < 4; ++jt) {
            accA[jt] = (f32x4){0.f, 0.f, 0.f, 0.f};
            #pragma unroll
            for (int kk = 0; kk < 4; ++kk) {
                bf16x8 bf = *(const bf16x8*)(kw + (jt * 16 + l15) * 136 + kk * 32 + quad * 8);
                accA[jt] = __builtin_amdgcn_mfma_f32_16x16x32_bf16(af[kk], bf, accA[jt], 0, 0, 0);
            }
        }
        // mask + Am + row sums
        {
            float rsum[4] = {0.f, 0.f, 0.f, 0.f};
            #pragma unroll
            for (int jt = 0; jt < 4; ++jt) {
                int j = jt * 16 + l15;
                #pragma unroll
                for (int r = 0; r < 4; ++r) {
                    int i = w * 16 + quad * 4 + r;
                    float val = (j <= i) ? accA[jt][r] : 0.f;
                    Am[i * 72 + j] = f2bf(val);
                    rsum[r] += val;
                }
            }
            #pragma unroll
            for (int off = 1; off < 16; off <<= 1) {
                rsum[0] += __shfl_xor(rsum[0], off);
                rsum[1] += __shfl_xor(rsum[1], off);
                rsum[2] += __shfl_xor(rsum[2], off);
                rsum[3] += __shfl_xor(rsum[3], off);
            }
            if (l15 == 0) {
                #pragma unroll
                for (int r = 0; r < 4; ++r) denA[w * 16 + quad * 4 + r] = rsum[r];
            }
        }
        if (tid < 64) {
            float s = 0.f;
            #pragma unroll
            for (int ss = 0; ss < 16; ++ss) {
                uint4 u = *(const uint4*)(qw + tid * 136 + ss * 8);
                s += bf2f((ushort)(u.x & 0xffff)) * psum[ss * 8 + 0] + bf2f((ushort)(u.x >> 16)) * psum[ss * 8 + 1];
                s += bf2f((ushort)(u.y & 0xffff)) * psum[ss * 8 + 2] + bf2f((ushort)(u.y >> 16)) * psum[ss * 8 + 3];
                s += bf2f((ushort)(u.z & 0xffff)) * psum[ss * 8 + 4] + bf2f((ushort)(u.z >> 16)) * psum[ss * 8 + 5];
                s += bf2f((ushort)(u.w & 0xffff)) * psum[ss * 8 + 6] + bf2f((ushort)(u.w >> 16)) * psum[ss * 8 + 7];
            }
            denI[tid] = s;
        }
        __syncthreads();

        // O = qw*P + Am*V   (vT persists from phase A, stride 88)
        f32x4 accO[2];
        #pragma unroll
        for (int mm = 0; mm < 2; ++mm) {
            accO[mm] = (f32x4){0.f, 0.f, 0.f, 0.f};
            #pragma unroll
            for (int kk = 0; kk < 4; ++kk) {
                bf16x8 bp = *(const bf16x8*)(Pt + (mm * 16 + l15) * 136 + kk * 32 + quad * 8);
                accO[mm] = __builtin_amdgcn_mfma_f32_16x16x32_bf16(af[kk], bp, accO[mm], 0, 0, 0);
            }
        }
        bf16x8 aA[2];
        #pragma unroll
        for (int kk = 0; kk < 2; ++kk)
            aA[kk] = *(const bf16x8*)(Am + (w * 16 + l15) * 72 + kk * 32 + quad * 8);
        #pragma unroll
        for (int mm = 0; mm < 2; ++mm)
            #pragma unroll
            for (int kk = 0; kk < 2; ++kk) {
                bf16x8 bv = *(const bf16x8*)(vT + (mm * 16 + l15) * 88 + kk * 32 + quad * 8);
                accO[mm] = __builtin_amdgcn_mfma_f32_16x16x32_bf16(aA[kk], bv, accO[mm], 0, 0, 0);
            }

        // repack O into region4 (qw dead after denI; separated by 2nd sync),
        // then one uint4 store per thread instead of 8 x 2B scattered stores.
        ushort* Orep = (ushort*)(smem + OFF_R4);
        const int nb = b >> 3, hh = b & 7;
        #pragma unroll
        for (int r = 0; r < 4; ++r) {
            int i = w * 16 + quad * 4 + r;
            float inv = 1.0f / fmaxf(denA[i] + denI[i], EPSV);
            #pragma unroll
            for (int mm = 0; mm < 2; ++mm)
                Orep[i * 40 + mm * 16 + l15] = f2bf(accO[mm][r] * inv);
        }
        __syncthreads();
        {
            int rr = tid >> 2, f = (tid & 3) * 8;
            uint4 vv = *(const uint4*)(Orep + rr * 40 + f);
            *(uint4*)(attn216 + (size_t)((l0 + rr) * 2 + nb) * EMBED + hh * 64 + m0b + f) = vv;
        }
    }
    __threadfence();
    grid.sync();    // B -> C: attn216 visible device-wide

    // =========================== Phase C ===================================
    {
        ushort* Ab = (ushort*)(smem + OFF_R4);
        ushort* Bb = (ushort*)(smem + OFF_R4 + 4608);
        {   // probs zero slice 2
            f32x4 z = {0.f, 0.f, 0.f, 0.f};
            size_t base = 2621440 + (size_t)bid * 3072 + tid;
            #pragma unroll
            for (int s = 0; s < 12; ++s)
                __builtin_nontemporal_store(z, (f32x4*)&probs4[base + s * 256]);
        }
        const int rt = bid >> 3, et = bid & 7;
        const int r0 = rt * 32, e0 = et * 64;
        const int it4 = w >> 1, jt0 = (w & 1) * 2;
        f32x4 acc4[2];
        acc4[0] = (f32x4){0.f, 0.f, 0.f, 0.f};
        acc4[1] = (f32x4){0.f, 0.f, 0.f, 0.f};

        for (int f0 = 0; f0 < EMBED; f0 += 64) {
            __syncthreads();
            {   // Ab: 32x64 bf16
                int rr = tid >> 3, ff = (tid & 7) * 8;
                *(uint4*)(Ab + rr * 72 + ff) = *(const uint4*)(attn216 + (size_t)(r0 + rr) * EMBED + f0 + ff);
            }
            #pragma unroll
            for (int s = 0; s < 2; ++s) {   // Bb: 64x64 bf16
                int e = tid + s * 256;
                int rr = e >> 3, ff = (e & 7) * 8;
                *(uint4*)(Bb + rr * 72 + ff) = *(const uint4*)(W16 + (size_t)(e0 + rr) * EMBED + f0 + ff);
            }
            __syncthreads();
            bf16x8 af2[2];
            #pragma unroll
            for (int kk = 0; kk < 2; ++kk)
                af2[kk] = *(const bf16x8*)(Ab + (it4 * 16 + l15) * 72 + kk * 32 + quad * 8);
            #pragma unroll
            for (int jj = 0; jj < 2; ++jj) {
                int jt = jt0 + jj;
                #pragma unroll
                for (int kk = 0; kk < 2; ++kk) {
                    bf16x8 bf = *(const bf16x8*)(Bb + (jt * 16 + l15) * 72 + kk * 32 + quad * 8);
                    acc4[jj] = __builtin_amdgcn_mfma_f32_16x16x32_bf16(af2[kk], bf, acc4[jj], 0, 0, 0);
                }
            }
        }
        #pragma unroll
        for (int jj = 0; jj < 2; ++jj) {
            int e = e0 + (jt0 + jj) * 16 + l15;
            float be = bias[e];
            int h = e >> 6, m = e & 63;
            #pragma unroll
            for (int r = 0; r < 4; ++r) {
                int rr = r0 + it4 * 16 + quad * 4 + r;
                int t = rr >> 1, n = rr & 1;
                __builtin_nontemporal_store(acc4[jj][r] + be,
                    &out[((size_t)(n * 8 + h) * TSEQ + t) * HIDV + m]);
            }
        }
    }
}

// ---------------------------------------------------------------------------
extern "C" void kernel_launch(void* const* d_in, const int* in_sizes, int n_in,
                              void* d_out, int out_size, void* d_ws, size_t ws_size,
                              hipStream_t stream) {
    const float* q = (const float*)d_in[0];
    const float* k = (const float*)d_in[1];
    const float* v = (const float*)d_in[2];
    const float* W = (const float*)d_in[3];
    const float* bias = (const float*)d_in[4];
    float* out = (float*)d_out;
    float* ws = (float*)d_ws;

    ushort* S16 = (ushort*)ws;                        // 2,097,152 bf16 (4 MB)
    float* ksum_ws = ws + 1048576;                    // 32,768 fp32
    ushort* attn216 = (ushort*)(ws + 1081344);        // 1,048,576 bf16 (2 MB)
    ushort* W16 = (ushort*)(ws + 1605632);            // 262,144 bf16 (0.5 MB)
    float4* probs4 = (float4*)(out + CTX_FLOATS);

    void* args[] = {(void*)&q, (void*)&k, (void*)&v, (void*)&W, (void*)&bias,
                    (void*)&S16, (void*)&ksum_ws, (void*)&attn216, (void*)&W16,
                    (void*)&out, (void*)&probs4};
    hipLaunchCooperativeKernel((void*)kFused, dim3(512), dim3(256), args, 0, stream);
}

// Round 2
// 116.667 us; speedup vs baseline: 2.8423x; 2.8423x over previous
//
#include <hip/hip_runtime.h>

#define TSEQ 1024
#define HIDV 64
#define NHEADS 16      // N*H = 2*8
#define LCH 64         // chunk length
#define NCH 16         // TSEQ/LCH
#define EMBED 512
#define CTX_FLOATS (NHEADS * TSEQ * HIDV)           // 1048576
#define EPSV 1e-6f
#define PIH 1.5707963267948966f

typedef short bf16x8 __attribute__((ext_vector_type(8)));
typedef float f32x4 __attribute__((ext_vector_type(4)));

__device__ __forceinline__ float relu_f(float x) { return fmaxf(x, 0.0f); }
__device__ __forceinline__ ushort f2bf(float f) {
    uint u = __float_as_uint(f);
    u += 0x7FFF + ((u >> 16) & 1);          // RNE
    return (ushort)(u >> 16);
}
__device__ __forceinline__ float bf2f(ushort h) { return __uint_as_float(((uint)h) << 16); }
__device__ __forceinline__ uint pk2(float a, float b) {
    return (uint)f2bf(a) | ((uint)f2bf(b) << 16);
}

// ---------------------------------------------------------------------------
// Kernel A: preprocess (qw16/kw16/vT16 bf16 export, swizzled) + chunk sums
// + W->bf16 + probs slice 0.  grid 512 x 256.
// ---------------------------------------------------------------------------
__global__ __launch_bounds__(256) void kA_chunksum(
    const float* __restrict__ Q, const float* __restrict__ K,
    const float* __restrict__ V, const float* __restrict__ W,
    ushort* __restrict__ S16, float* __restrict__ ksumws,
    ushort* __restrict__ W16,
    ushort* __restrict__ qw16, ushort* __restrict__ kw16,
    ushort* __restrict__ vT16, float4* __restrict__ probs4)
{
    __shared__ ushort kwT[128 * 88];   // [dd][i] weighted bf16
    __shared__ ushort vT1[32 * 88];    // [m-half][i]
    const int rb = blockIdx.x;
    const int bid = ((rb & 7) << 6) | (rb >> 3);   // XCD swizzle (bijective 8x64)
    const int tid = threadIdx.x;

    {   // probs zero slice 0: 1,310,720 f4 (20 MB), nontemporal
        f32x4 z = {0.f, 0.f, 0.f, 0.f};
        size_t base = (size_t)rb * 2560 + tid;
        #pragma unroll
        for (int s = 0; s < 10; ++s)
            __builtin_nontemporal_store(z, (f32x4*)&probs4[base + s * 256]);
    }
    {   // W (512x512 fp32) -> bf16
        int g = rb * 128 + (tid & 127);
        if (tid < 128) {
            float4 w4 = *(const float4*)(W + (size_t)g * 4);
            *(uint2*)(W16 + (size_t)g * 4) = make_uint2(pk2(w4.x, w4.y), pk2(w4.z, w4.w));
        }
    }

    const int pair = bid >> 1, mh = bid & 1, m0b = mh * 32;
    const int b = pair >> 4, c = pair & 15;
    const int l0 = c * LCH;

    #pragma unroll
    for (int s = 0; s < 2; ++s) {
        int e = tid + s * 256;               // 512 tasks: 64 i x 8 octs
        int i = e >> 3, o = e & 7, d = o * 8;
        float si, ci;
        __sincosf(PIH * (float)(l0 + i + 1) * (1.0f / 1024.0f), &si, &ci);
        const float* kp = K + (size_t)(b * TSEQ + l0 + i) * HIDV + d;
        float4 ka = *(const float4*)kp;
        float4 kb = *(const float4*)(kp + 4);
        float kv[8] = {relu_f(ka.x), relu_f(ka.y), relu_f(ka.z), relu_f(ka.w),
                       relu_f(kb.x), relu_f(kb.y), relu_f(kb.z), relu_f(kb.w)};
        #pragma unroll
        for (int j = 0; j < 8; ++j) {
            kwT[(d + j) * 88 + i] = f2bf(si * kv[j]);
            kwT[(d + 64 + j) * 88 + i] = f2bf(ci * kv[j]);
        }
        if (mh == 0) {
            // kw16: row-major [i][128 dd] bf16, XOR-swizzled 16B granules
            uint4 usi = make_uint4(pk2(si*kv[0], si*kv[1]), pk2(si*kv[2], si*kv[3]),
                                   pk2(si*kv[4], si*kv[5]), pk2(si*kv[6], si*kv[7]));
            uint4 uci = make_uint4(pk2(ci*kv[0], ci*kv[1]), pk2(ci*kv[2], ci*kv[3]),
                                   pk2(ci*kv[4], ci*kv[5]), pk2(ci*kv[6], ci*kv[7]));
            char* rowp = (char*)kw16 + (size_t)(b * TSEQ + l0 + i) * 256;
            *(uint4*)(rowp + ((d * 2) ^ ((i & 7) << 4))) = usi;
            *(uint4*)(rowp + ((128 + d * 2) ^ ((i & 7) << 4))) = uci;
            // qw16: row-major linear (read as per-lane fragments, no LDS)
            const float* qp = Q + (size_t)(b * TSEQ + l0 + i) * HIDV + d;
            float4 qa = *(const float4*)qp;
            float4 qb = *(const float4*)(qp + 4);
            float qv[8] = {relu_f(qa.x), relu_f(qa.y), relu_f(qa.z), relu_f(qa.w),
                           relu_f(qb.x), relu_f(qb.y), relu_f(qb.z), relu_f(qb.w)};
            ushort* qrow = qw16 + (size_t)(b * TSEQ + l0 + i) * 128;
            *(uint4*)(qrow + d) = make_uint4(pk2(si*qv[0], si*qv[1]), pk2(si*qv[2], si*qv[3]),
                                             pk2(si*qv[4], si*qv[5]), pk2(si*qv[6], si*qv[7]));
            *(uint4*)(qrow + 64 + d) = make_uint4(pk2(ci*qv[0], ci*qv[1]), pk2(ci*qv[2], ci*qv[3]),
                                                  pk2(ci*qv[4], ci*qv[5]), pk2(ci*qv[6], ci*qv[7]));
        }
    }
    #pragma unroll
    for (int s = 0; s < 2; ++s) {
        int e = tid + s * 256;               // f4 over 64 i x 32 m
        int i = e >> 3, mf = (e & 7) * 4;
        float4 v4 = *(const float4*)(V + ((size_t)(l0 + i) * NHEADS + b) * HIDV + m0b + mf);
        vT1[(mf + 0) * 88 + i] = f2bf(v4.x);
        vT1[(mf + 1) * 88 + i] = f2bf(v4.y);
        vT1[(mf + 2) * 88 + i] = f2bf(v4.z);
        vT1[(mf + 3) * 88 + i] = f2bf(v4.w);
    }
    __syncthreads();

    const int w = tid >> 6, lane = tid & 63;
    const int quad = lane >> 4, l15 = lane & 15;

    bf16x8 bfv[2][2];
    #pragma unroll
    for (int mt = 0; mt < 2; ++mt)
        #pragma unroll
        for (int kk = 0; kk < 2; ++kk)
            bfv[mt][kk] = *(const bf16x8*)(vT1 + (mt * 16 + l15) * 88 + kk * 32 + quad * 8);

    f32x4 acc[2][2];
    #pragma unroll
    for (int ii = 0; ii < 2; ++ii)
        #pragma unroll
        for (int mt = 0; mt < 2; ++mt) acc[ii][mt] = (f32x4){0.f, 0.f, 0.f, 0.f};
    #pragma unroll
    for (int ii = 0; ii < 2; ++ii) {
        int itv = w + ii * 4;                // dd-tile 0..7
        #pragma unroll
        for (int kk = 0; kk < 2; ++kk) {
            bf16x8 af = *(const bf16x8*)(kwT + (itv * 16 + l15) * 88 + kk * 32 + quad * 8);
            #pragma unroll
            for (int mt = 0; mt < 2; ++mt)
                acc[ii][mt] = __builtin_amdgcn_mfma_f32_16x16x32_bf16(af, bfv[mt][kk], acc[ii][mt], 0, 0, 0);
        }
    }
    ushort* SpT = S16 + (size_t)pair * 8192;
    #pragma unroll
    for (int ii = 0; ii < 2; ++ii)
        #pragma unroll
        for (int mt = 0; mt < 2; ++mt) {
            int m = m0b + mt * 16 + l15;
            int ddb = (w + ii * 4) * 16 + quad * 4;
            uint2 pk = make_uint2(pk2(acc[ii][mt][0], acc[ii][mt][1]),
                                  pk2(acc[ii][mt][2], acc[ii][mt][3]));
            *(uint2*)(SpT + m * 128 + ddb) = pk;
        }
    {   // vT16 export: per-(pair,mh) 4KB blob [32 m][64 i], swizzled
        int m = tid >> 3, o = tid & 7;
        uint4 val = *(const uint4*)(vT1 + m * 88 + o * 8);
        char* vb = (char*)(vT16 + (size_t)(pair * 2 + mh) * 2048);
        *(uint4*)(vb + ((m * 128 + o * 16) ^ ((m & 7) << 4))) = val;
    }
    if (mh == 0 && tid < 128) {
        float ssum = 0.f;
        #pragma unroll
        for (int ss = 0; ss < 8; ++ss) {
            uint4 u = *(const uint4*)(kwT + tid * 88 + ss * 8);
            ssum += bf2f((ushort)(u.x & 0xffff)) + bf2f((ushort)(u.x >> 16));
            ssum += bf2f((ushort)(u.y & 0xffff)) + bf2f((ushort)(u.y >> 16));
            ssum += bf2f((ushort)(u.z & 0xffff)) + bf2f((ushort)(u.z >> 16));
            ssum += bf2f((ushort)(u.w & 0xffff)) + bf2f((ushort)(u.w >> 16));
        }
        ksumws[(size_t)pair * 128 + tid] = ssum;
    }
}

// ---------------------------------------------------------------------------
// Kernel B: attention. All staging is linear bf16 copies of kA's exports;
// K/V LDS tiles unpadded + XOR-swizzled (conflict-free ds_read_b128).
// LDS 39424 B.  grid 512 x 256.
// ---------------------------------------------------------------------------
#define B_KW 0          // ushort[64][128]  swizzled   (later: Orep[64][40])
#define B_VT 16384      // ushort[32][64]   swizzled
#define B_PT 20480      // ushort[32][136]
#define B_AM 29184      // ushort[64][72]
#define B_PS 38400      // float[128]
#define B_DA 38912      // float[64]
#define B_DI 39168      // float[64]
#define B_BYTES 39424

__global__ __launch_bounds__(256) void kB_attn(
    const ushort* __restrict__ qw16, const ushort* __restrict__ kw16,
    const ushort* __restrict__ vT16,
    const ushort* __restrict__ S16, const float* __restrict__ ksumws,
    ushort* __restrict__ attn216, float4* __restrict__ probs4)
{
    __shared__ __align__(16) char smem[B_BYTES];
    ushort* Pt = (ushort*)(smem + B_PT);
    ushort* Am = (ushort*)(smem + B_AM);
    float* psum = (float*)(smem + B_PS);
    float* denA = (float*)(smem + B_DA);
    float* denI = (float*)(smem + B_DI);

    const int rb = blockIdx.x;
    const int bid = ((rb & 7) << 6) | (rb >> 3);   // same XCD swizzle as kA
    const int tid = threadIdx.x;
    const int w = tid >> 6, lane = tid & 63;
    const int quad = lane >> 4, l15 = lane & 15;
    const int pair = bid >> 1, mh = bid & 1, m0b = mh * 32;
    const int b = pair >> 4, c = pair & 15;
    const int l0 = c * LCH;

    // stage kw (16KB) + vT (4KB): linear copies (swizzle pre-baked by kA)
    {
        const uint4* gk = (const uint4*)(kw16 + (size_t)(b * TSEQ + l0) * 128);
        uint4* lk = (uint4*)(smem + B_KW);
        #pragma unroll
        for (int s = 0; s < 4; ++s) lk[tid + s * 256] = gk[tid + s * 256];
        const uint4* gv = (const uint4*)(vT16 + (size_t)(pair * 2 + mh) * 2048);
        ((uint4*)(smem + B_VT))[tid] = gv[tid];
    }

    {   // probs zero slice 1 (nontemporal)
        f32x4 z = {0.f, 0.f, 0.f, 0.f};
        size_t base = 1310720 + (size_t)rb * 2560 + tid;
        #pragma unroll
        for (int s = 0; s < 10; ++s)
            __builtin_nontemporal_store(z, (f32x4*)&probs4[base + s * 256]);
    }

    // Q fragments straight from global (row-major linear qw16)
    bf16x8 af[4];
    {
        const ushort* qrow = qw16 + (size_t)(b * TSEQ + l0 + w * 16 + l15) * 128 + quad * 8;
        #pragma unroll
        for (int kk = 0; kk < 4; ++kk)
            af[kk] = *(const bf16x8*)(qrow + kk * 32);
    }

    // inline exclusive prefix: Pt[ml][dd] = sum_{cp<c} S[b][cp][m0b+ml][dd]
    {
        const int ml = tid >> 3, dd0 = (tid & 7) * 16;
        const ushort* Sb = S16 + ((size_t)b * NCH) * 8192 + (m0b + ml) * 128 + dd0;
        float accp[16];
        #pragma unroll
        for (int u = 0; u < 16; ++u) accp[u] = 0.f;
        for (int cp = 0; cp < c; ++cp) {
            const ushort* Sp = Sb + (size_t)cp * 8192;
            uint4 u0 = *(const uint4*)(Sp);
            uint4 u1 = *(const uint4*)(Sp + 8);
            uint uu[8] = {u0.x, u0.y, u0.z, u0.w, u1.x, u1.y, u1.z, u1.w};
            #pragma unroll
            for (int p = 0; p < 8; ++p) {
                accp[p * 2 + 0] += bf2f((ushort)(uu[p] & 0xffff));
                accp[p * 2 + 1] += bf2f((ushort)(uu[p] >> 16));
            }
        }
        uint pkv[8];
        #pragma unroll
        for (int p = 0; p < 8; ++p) pkv[p] = pk2(accp[p * 2], accp[p * 2 + 1]);
        *(uint4*)(Pt + ml * 136 + dd0) = make_uint4(pkv[0], pkv[1], pkv[2], pkv[3]);
        *(uint4*)(Pt + ml * 136 + dd0 + 8) = make_uint4(pkv[4], pkv[5], pkv[6], pkv[7]);
    }
    if (tid < 128) {
        float s = 0.f;
        const float* Kb = ksumws + (size_t)b * NCH * 128 + tid;
        for (int cp = 0; cp < c; ++cp) s += Kb[cp * 128];
        psum[tid] = s;
    }
    __syncthreads();

    // QK^T: bf from swizzled kw LDS
    f32x4 accA[4];
    #pragma unroll
    for (int jt = 0; jt < 4; ++jt) {
        accA[jt] = (f32x4){0.f, 0.f, 0.f, 0.f};
        int row = jt * 16 + l15;
        const char* rowp = smem + B_KW + row * 256;
        #pragma unroll
        for (int kk = 0; kk < 4; ++kk) {
            bf16x8 bf = *(const bf16x8*)(rowp + (((kk * 64 + quad * 16)) ^ ((l15 & 7) << 4)));
            accA[jt] = __builtin_amdgcn_mfma_f32_16x16x32_bf16(af[kk], bf, accA[jt], 0, 0, 0);
        }
    }
    // mask + Am + row sums -> denA
    {
        float rsum[4] = {0.f, 0.f, 0.f, 0.f};
        #pragma unroll
        for (int jt = 0; jt < 4; ++jt) {
            int j = jt * 16 + l15;
            #pragma unroll
            for (int r = 0; r < 4; ++r) {
                int i = w * 16 + quad * 4 + r;
                float val = (j <= i) ? accA[jt][r] : 0.f;
                Am[i * 72 + j] = f2bf(val);
                rsum[r] += val;
            }
        }
        #pragma unroll
        for (int off = 1; off < 16; off <<= 1) {
            rsum[0] += __shfl_xor(rsum[0], off);
            rsum[1] += __shfl_xor(rsum[1], off);
            rsum[2] += __shfl_xor(rsum[2], off);
            rsum[3] += __shfl_xor(rsum[3], off);
        }
        if (l15 == 0) {
            #pragma unroll
            for (int r = 0; r < 4; ++r) denA[w * 16 + quad * 4 + r] = rsum[r];
        }
    }
    // denI from af registers x psum (per-lane partial over 32 dd, quad-reduce)
    {
        float di = 0.f;
        #pragma unroll
        for (int kk = 0; kk < 4; ++kk) {
            f32x4 p0 = *(const f32x4*)(psum + kk * 32 + quad * 8);
            f32x4 p1 = *(const f32x4*)(psum + kk * 32 + quad * 8 + 4);
            di += bf2f((ushort)af[kk][0]) * p0.x + bf2f((ushort)af[kk][1]) * p0.y;
            di += bf2f((ushort)af[kk][2]) * p0.z + bf2f((ushort)af[kk][3]) * p0.w;
            di += bf2f((ushort)af[kk][4]) * p1.x + bf2f((ushort)af[kk][5]) * p1.y;
            di += bf2f((ushort)af[kk][6]) * p1.z + bf2f((ushort)af[kk][7]) * p1.w;
        }
        di += __shfl_xor(di, 16);
        di += __shfl_xor(di, 32);
        if (lane < 16) denI[w * 16 + l15] = di;
    }
    __syncthreads();

    // O = qw*Pt + Am*vT
    f32x4 accO[2];
    #pragma unroll
    for (int mm = 0; mm < 2; ++mm) {
        accO[mm] = (f32x4){0.f, 0.f, 0.f, 0.f};
        #pragma unroll
        for (int kk = 0; kk < 4; ++kk) {
            bf16x8 bp = *(const bf16x8*)(Pt + (mm * 16 + l15) * 136 + kk * 32 + quad * 8);
            accO[mm] = __builtin_amdgcn_mfma_f32_16x16x32_bf16(af[kk], bp, accO[mm], 0, 0, 0);
        }
    }
    bf16x8 aA[2];
    #pragma unroll
    for (int kk = 0; kk < 2; ++kk)
        aA[kk] = *(const bf16x8*)(Am + (w * 16 + l15) * 72 + kk * 32 + quad * 8);
    #pragma unroll
    for (int mm = 0; mm < 2; ++mm) {
        int row = mm * 16 + l15;
        const char* vrow = smem + B_VT + row * 128;
        #pragma unroll
        for (int kk = 0; kk < 2; ++kk) {
            bf16x8 bv = *(const bf16x8*)(vrow + (((kk * 64 + quad * 16)) ^ ((l15 & 7) << 4)));
            accO[mm] = __builtin_amdgcn_mfma_f32_16x16x32_bf16(aA[kk], bv, accO[mm], 0, 0, 0);
        }
    }

    // normalize + repack into kw region (dead after QK^T), then uint4 stores
    ushort* Orep = (ushort*)(smem + B_KW);
    const int nb = b >> 3, hh = b & 7;
    #pragma unroll
    for (int r = 0; r < 4; ++r) {
        int i = w * 16 + quad * 4 + r;
        float inv = 1.0f / fmaxf(denA[i] + denI[i], EPSV);
        #pragma unroll
        for (int mm = 0; mm < 2; ++mm)
            Orep[i * 40 + mm * 16 + l15] = f2bf(accO[mm][r] * inv);
    }
    __syncthreads();
    {
        int rr = tid >> 2, f = (tid & 3) * 8;
        uint4 vv = *(const uint4*)(Orep + rr * 40 + f);
        *(uint4*)(attn216 + (size_t)((l0 + rr) * 2 + nb) * EMBED + hh * 64 + m0b + f) = vv;
    }
}

// ---------------------------------------------------------------------------
// Kernel C: out projection (bf16 x bf16).  32x64 tiles, grid 512 x 256.
// ---------------------------------------------------------------------------
__global__ __launch_bounds__(256) void kC_outproj(
    const ushort* __restrict__ A16, const ushort* __restrict__ W16,
    const float* __restrict__ bias, float* __restrict__ out,
    float4* __restrict__ probs4)
{
    __shared__ ushort Ab[32 * 72];
    __shared__ ushort Bb[64 * 72];
    const int bid = blockIdx.x;
    const int tid = threadIdx.x;
    {   // probs zero slice 2: 1,572,864 f4 (nontemporal)
        f32x4 z = {0.f, 0.f, 0.f, 0.f};
        size_t base = 2621440 + (size_t)bid * 3072 + tid;
        #pragma unroll
        for (int s = 0; s < 12; ++s)
            __builtin_nontemporal_store(z, (f32x4*)&probs4[base + s * 256]);
    }
    const int rt = bid >> 3, et = bid & 7;
    const int r0 = rt * 32, e0 = et * 64;
    const int w = tid >> 6, lane = tid & 63;
    const int quad = lane >> 4, l15 = lane & 15;
    const int it4 = w >> 1, jt0 = (w & 1) * 2;
    f32x4 acc4[2];
    acc4[0] = (f32x4){0.f, 0.f, 0.f, 0.f};
    acc4[1] = (f32x4){0.f, 0.f, 0.f, 0.f};

    for (int f0 = 0; f0 < EMBED; f0 += 64) {
        __syncthreads();
        {   // Ab: 32x64 bf16
            int rr = tid >> 3, ff = (tid & 7) * 8;
            *(uint4*)(Ab + rr * 72 + ff) = *(const uint4*)(A16 + (size_t)(r0 + rr) * EMBED + f0 + ff);
        }
        #pragma unroll
        for (int s = 0; s < 2; ++s) {   // Bb: 64x64 bf16
            int e = tid + s * 256;
            int rr = e >> 3, ff = (e & 7) * 8;
            *(uint4*)(Bb + rr * 72 + ff) = *(const uint4*)(W16 + (size_t)(e0 + rr) * EMBED + f0 + ff);
        }
        __syncthreads();
        bf16x8 af2[2];
        #pragma unroll
        for (int kk = 0; kk < 2; ++kk)
            af2[kk] = *(const bf16x8*)(Ab + (it4 * 16 + l15) * 72 + kk * 32 + quad * 8);
        #pragma unroll
        for (int jj = 0; jj < 2; ++jj) {
            int jt = jt0 + jj;
            #pragma unroll
            for (int kk = 0; kk < 2; ++kk) {
                bf16x8 bf = *(const bf16x8*)(Bb + (jt * 16 + l15) * 72 + kk * 32 + quad * 8);
                acc4[jj] = __builtin_amdgcn_mfma_f32_16x16x32_bf16(af2[kk], bf, acc4[jj], 0, 0, 0);
            }
        }
    }
    #pragma unroll
    for (int jj = 0; jj < 2; ++jj) {
        int e = e0 + (jt0 + jj) * 16 + l15;
        float be = bias[e];
        int h = e >> 6, m = e & 63;
        #pragma unroll
        for (int r = 0; r < 4; ++r) {
            int rr = r0 + it4 * 16 + quad * 4 + r;
            int t = rr >> 1, n = rr & 1;
            __builtin_nontemporal_store(acc4[jj][r] + be,
                &out[((size_t)(n * 8 + h) * TSEQ + t) * HIDV + m]);
        }
    }
}

// ---------------------------------------------------------------------------
extern "C" void kernel_launch(void* const* d_in, const int* in_sizes, int n_in,
                              void* d_out, int out_size, void* d_ws, size_t ws_size,
                              hipStream_t stream) {
    const float* q = (const float*)d_in[0];
    const float* k = (const float*)d_in[1];
    const float* v = (const float*)d_in[2];
    const float* W = (const float*)d_in[3];
    const float* bias = (const float*)d_in[4];
    float* out = (float*)d_out;
    float* ws = (float*)d_ws;

    ushort* S16 = (ushort*)ws;                        // 4 MB
    float* ksum_ws = ws + 1048576;                    // 128 KB
    ushort* attn216 = (ushort*)(ws + 1081344);        // 2 MB
    ushort* W16 = (ushort*)(ws + 1605632);            // 0.5 MB
    ushort* qw16 = (ushort*)(ws + 1736704);           // 4 MB
    ushort* kw16 = (ushort*)(ws + 2785280);           // 4 MB
    ushort* vT16 = (ushort*)(ws + 3833856);           // 2 MB
    float4* probs4 = (float4*)(out + CTX_FLOATS);

    kA_chunksum<<<dim3(512), dim3(256), 0, stream>>>(q, k, v, W, S16, ksum_ws, W16,
                                                     qw16, kw16, vT16, probs4);
    kB_attn<<<dim3(512), dim3(256), 0, stream>>>(qw16, kw16, vT16, S16, ksum_ws,
                                                 attn216, probs4);
    kC_outproj<<<dim3(512), dim3(256), 0, stream>>>(attn216, W16, bias, out, probs4);
}

// Round 3
// 115.499 us; speedup vs baseline: 2.8710x; 1.0101x over previous
//
#include <hip/hip_runtime.h>

#define TSEQ 1024
#define HIDV 64
#define NHEADS 16      // N*H = 2*8
#define LCH 64         // chunk length
#define NCH 16         // TSEQ/LCH
#define EMBED 512
#define CTX_FLOATS (NHEADS * TSEQ * HIDV)           // 1048576
#define EPSV 1e-6f
#define PIH 1.5707963267948966f

typedef short bf16x8 __attribute__((ext_vector_type(8)));
typedef float f32x4 __attribute__((ext_vector_type(4)));

__device__ __forceinline__ float relu_f(float x) { return fmaxf(x, 0.0f); }
__device__ __forceinline__ ushort f2bf(float f) {
    uint u = __float_as_uint(f);
    u += 0x7FFF + ((u >> 16) & 1);          // RNE
    return (ushort)(u >> 16);
}
__device__ __forceinline__ float bf2f(ushort h) { return __uint_as_float(((uint)h) << 16); }
__device__ __forceinline__ uint pk2(float a, float b) {
    return (uint)f2bf(a) | ((uint)f2bf(b) << 16);
}

// ---------------------------------------------------------------------------
// Kernel A: chunk sums (m-half split) + W->bf16 + probs-zero slice 0.
// grid 512 x 256.  S^T stored bf16 [m][dd] per (b,c); ksum raw per-chunk.
// ---------------------------------------------------------------------------
__global__ __launch_bounds__(256) void kA_chunksum(
    const float* __restrict__ K, const float* __restrict__ V,
    const float* __restrict__ W,
    ushort* __restrict__ S16, float* __restrict__ ksumws,
    ushort* __restrict__ W16, float4* __restrict__ probs4)
{
    __shared__ ushort kwT[128 * 88];   // [dd][i] weighted bf16
    __shared__ ushort vT1[32 * 88];    // [m-half][i]
    const int bid = blockIdx.x;
    const int tid = threadIdx.x;

    {   // probs zero slice 0: 1,310,720 f4 (20 MB), nontemporal
        f32x4 z = {0.f, 0.f, 0.f, 0.f};
        size_t base = (size_t)bid * 2560 + tid;
        #pragma unroll
        for (int s = 0; s < 10; ++s)
            __builtin_nontemporal_store(z, (f32x4*)&probs4[base + s * 256]);
    }
    {   // W (512x512 fp32) -> bf16: 65536 f4 over 512 blocks
        int g = bid * 128 + (tid & 127);
        if (tid < 128) {
            float4 w4 = *(const float4*)(W + (size_t)g * 4);
            *(uint2*)(W16 + (size_t)g * 4) = make_uint2(pk2(w4.x, w4.y), pk2(w4.z, w4.w));
        }
    }

    const int pair = bid >> 1, mh = bid & 1, m0b = mh * 32;
    const int b = pair >> 4, c = pair & 15;
    const int l0 = c * LCH;

    #pragma unroll
    for (int s = 0; s < 4; ++s) {
        int e = tid + s * 256;               // f4 over 64x64
        int i = e >> 4, d = (e & 15) * 4;
        float4 k4 = *(const float4*)(K + (size_t)(b * TSEQ + l0 + i) * HIDV + d);
        float si, ci;
        __sincosf(PIH * (float)(l0 + i + 1) * (1.0f / 1024.0f), &si, &ci);
        float kv[4] = {relu_f(k4.x), relu_f(k4.y), relu_f(k4.z), relu_f(k4.w)};
        #pragma unroll
        for (int j = 0; j < 4; ++j) {
            kwT[(d + j) * 88 + i] = f2bf(si * kv[j]);
            kwT[(d + 64 + j) * 88 + i] = f2bf(ci * kv[j]);
        }
    }
    #pragma unroll
    for (int s = 0; s < 2; ++s) {
        int e = tid + s * 256;               // f4 over 64 i x 32 m
        int i = e >> 3, mf = (e & 7) * 4;
        float4 v4 = *(const float4*)(V + ((size_t)(l0 + i) * NHEADS + b) * HIDV + m0b + mf);
        vT1[(mf + 0) * 88 + i] = f2bf(v4.x);
        vT1[(mf + 1) * 88 + i] = f2bf(v4.y);
        vT1[(mf + 2) * 88 + i] = f2bf(v4.z);
        vT1[(mf + 3) * 88 + i] = f2bf(v4.w);
    }
    __syncthreads();

    const int w = tid >> 6, lane = tid & 63;
    const int quad = lane >> 4, l15 = lane & 15;

    bf16x8 bfv[2][2];
    #pragma unroll
    for (int mt = 0; mt < 2; ++mt)
        #pragma unroll
        for (int kk = 0; kk < 2; ++kk)
            bfv[mt][kk] = *(const bf16x8*)(vT1 + (mt * 16 + l15) * 88 + kk * 32 + quad * 8);

    f32x4 acc[2][2];
    #pragma unroll
    for (int ii = 0; ii < 2; ++ii)
        #pragma unroll
        for (int mt = 0; mt < 2; ++mt) acc[ii][mt] = (f32x4){0.f, 0.f, 0.f, 0.f};
    #pragma unroll
    for (int ii = 0; ii < 2; ++ii) {
        int itv = w + ii * 4;                // dd-tile 0..7
        #pragma unroll
        for (int kk = 0; kk < 2; ++kk) {
            bf16x8 af = *(const bf16x8*)(kwT + (itv * 16 + l15) * 88 + kk * 32 + quad * 8);
            #pragma unroll
            for (int mt = 0; mt < 2; ++mt)
                acc[ii][mt] = __builtin_amdgcn_mfma_f32_16x16x32_bf16(af, bfv[mt][kk], acc[ii][mt], 0, 0, 0);
        }
    }
    ushort* SpT = S16 + (size_t)pair * 8192;
    #pragma unroll
    for (int ii = 0; ii < 2; ++ii)
        #pragma unroll
        for (int mt = 0; mt < 2; ++mt) {
            int m = m0b + mt * 16 + l15;
            int ddb = (w + ii * 4) * 16 + quad * 4;
            uint2 pk = make_uint2(pk2(acc[ii][mt][0], acc[ii][mt][1]),
                                  pk2(acc[ii][mt][2], acc[ii][mt][3]));
            *(uint2*)(SpT + m * 128 + ddb) = pk;
        }
    if (mh == 0 && tid < 128) {
        float ssum = 0.f;
        #pragma unroll
        for (int ss = 0; ss < 8; ++ss) {
            uint4 u = *(const uint4*)(kwT + tid * 88 + ss * 8);
            ssum += bf2f((ushort)(u.x & 0xffff)) + bf2f((ushort)(u.x >> 16));
            ssum += bf2f((ushort)(u.y & 0xffff)) + bf2f((ushort)(u.y >> 16));
            ssum += bf2f((ushort)(u.z & 0xffff)) + bf2f((ushort)(u.z >> 16));
            ssum += bf2f((ushort)(u.w & 0xffff)) + bf2f((ushort)(u.w >> 16));
        }
        ksumws[(size_t)pair * 128 + tid] = ssum;
    }
}

// ---------------------------------------------------------------------------
// Kernel B: attention with INLINE prefix.  2 blocks per (b,c): m-halves.
// grid 512 x 256.  LDS 58368 B -> 2 blocks/CU.
// c-load-balance: blocks i and i+256 co-schedule on a CU; XOR-30 remap pairs
// chunk c with 15-c so no CU gets two prefix-heavy (c=15) blocks.
// ---------------------------------------------------------------------------
#define SMEM_BYTES 58368
#define OFF_QW 0          // ushort[64*136]  (epilogue: Orep[64*40])
#define OFF_KW 17408      // ushort[64*136]
#define OFF_PT 34816      // ushort[32*136]
#define OFF_VT 43520      // ushort[32*72]
#define OFF_AM 48128      // ushort[64*72]
#define OFF_PSUM 57344    // float[128]
#define OFF_DENA 57856    // float[64]
#define OFF_DENI 58112    // float[64]

__global__ __launch_bounds__(256) void kB_attn(
    const float* __restrict__ Q, const float* __restrict__ K,
    const float* __restrict__ V,
    const ushort* __restrict__ S16, const float* __restrict__ ksumws,
    ushort* __restrict__ attn216, float4* __restrict__ probs4)
{
    __shared__ __align__(16) char smem[SMEM_BYTES];
    ushort* qw = (ushort*)(smem + OFF_QW);
    ushort* kw = (ushort*)(smem + OFF_KW);
    ushort* Pt = (ushort*)(smem + OFF_PT);
    ushort* vT = (ushort*)(smem + OFF_VT);
    ushort* Am = (ushort*)(smem + OFF_AM);
    float* psum = (float*)(smem + OFF_PSUM);
    float* denA = (float*)(smem + OFF_DENA);
    float* denI = (float*)(smem + OFF_DENI);

    const int rb = blockIdx.x;
    const int bid = (rb < 256) ? rb : (rb ^ 30);   // pair c with 15-c per CU
    const int tid = threadIdx.x;
    const int w = tid >> 6, lane = tid & 63;
    const int quad = lane >> 4, l15 = lane & 15;

    {   // probs zero slice 1: 1,310,720 f4, nontemporal
        f32x4 z = {0.f, 0.f, 0.f, 0.f};
        size_t base = 1310720 + (size_t)rb * 2560 + tid;
        #pragma unroll
        for (int s = 0; s < 10; ++s)
            __builtin_nontemporal_store(z, (f32x4*)&probs4[base + s * 256]);
    }

    const int pair = bid >> 1, mh = bid & 1, m0b = mh * 32;
    const int b = pair >> 4, c = pair & 15;
    const int l0 = c * LCH;

    // --- inline exclusive prefix: P[ml][dd] = sum_{cp<c} S[b][cp][m0b+ml][dd]
    {
        const int ml = tid >> 3, dd0 = (tid & 7) * 16;
        const ushort* Sb = S16 + ((size_t)b * NCH) * 8192 + (m0b + ml) * 128 + dd0;
        float accp[16];
        #pragma unroll
        for (int u = 0; u < 16; ++u) accp[u] = 0.f;
        for (int cp = 0; cp < c; ++cp) {
            const ushort* Sp = Sb + (size_t)cp * 8192;
            uint4 u0 = *(const uint4*)(Sp);
            uint4 u1 = *(const uint4*)(Sp + 8);
            uint uu[8] = {u0.x, u0.y, u0.z, u0.w, u1.x, u1.y, u1.z, u1.w};
            #pragma unroll
            for (int p = 0; p < 8; ++p) {
                accp[p * 2 + 0] += bf2f((ushort)(uu[p] & 0xffff));
                accp[p * 2 + 1] += bf2f((ushort)(uu[p] >> 16));
            }
        }
        uint pkv[8];
        #pragma unroll
        for (int p = 0; p < 8; ++p) pkv[p] = pk2(accp[p * 2], accp[p * 2 + 1]);
        *(uint4*)(Pt + ml * 136 + dd0) = make_uint4(pkv[0], pkv[1], pkv[2], pkv[3]);
        *(uint4*)(Pt + ml * 136 + dd0 + 8) = make_uint4(pkv[4], pkv[5], pkv[6], pkv[7]);
    }
    if (tid < 128) {
        float s = 0.f;
        const float* Kb = ksumws + (size_t)b * NCH * 128 + tid;
        for (int cp = 0; cp < c; ++cp) s += Kb[cp * 128];
        psum[tid] = s;
    }

    #pragma unroll
    for (int s = 0; s < 4; ++s) {
        int e = tid + s * 256;
        int i = e >> 4, d = (e & 15) * 4;
        float si, ci;
        __sincosf(PIH * (float)(l0 + i + 1) * (1.0f / 1024.0f), &si, &ci);
        float4 q4 = *(const float4*)(Q + (size_t)(b * TSEQ + l0 + i) * HIDV + d);
        float qv[4] = {relu_f(q4.x), relu_f(q4.y), relu_f(q4.z), relu_f(q4.w)};
        *(uint2*)(qw + i * 136 + d) = make_uint2(pk2(si * qv[0], si * qv[1]), pk2(si * qv[2], si * qv[3]));
        *(uint2*)(qw + i * 136 + 64 + d) = make_uint2(pk2(ci * qv[0], ci * qv[1]), pk2(ci * qv[2], ci * qv[3]));
        float4 k4 = *(const float4*)(K + (size_t)(b * TSEQ + l0 + i) * HIDV + d);
        float kv[4] = {relu_f(k4.x), relu_f(k4.y), relu_f(k4.z), relu_f(k4.w)};
        *(uint2*)(kw + i * 136 + d) = make_uint2(pk2(si * kv[0], si * kv[1]), pk2(si * kv[2], si * kv[3]));
        *(uint2*)(kw + i * 136 + 64 + d) = make_uint2(pk2(ci * kv[0], ci * kv[1]), pk2(ci * kv[2], ci * kv[3]));
    }
    #pragma unroll
    for (int s = 0; s < 2; ++s) {
        int e = tid + s * 256;
        int j = e >> 3, mf = (e & 7) * 4;
        float4 v4 = *(const float4*)(V + ((size_t)(l0 + j) * NHEADS + b) * HIDV + m0b + mf);
        vT[(mf + 0) * 72 + j] = f2bf(v4.x);
        vT[(mf + 1) * 72 + j] = f2bf(v4.y);
        vT[(mf + 2) * 72 + j] = f2bf(v4.z);
        vT[(mf + 3) * 72 + j] = f2bf(v4.w);
    }
    __syncthreads();

    const int it = w;
    bf16x8 af[4];
    #pragma unroll
    for (int kk = 0; kk < 4; ++kk)
        af[kk] = *(const bf16x8*)(qw + (it * 16 + l15) * 136 + kk * 32 + quad * 8);

    // QK^T
    f32x4 accA[4];
    #pragma unroll
    for (int jt = 0; jt < 4; ++jt) {
        accA[jt] = (f32x4){0.f, 0.f, 0.f, 0.f};
        #pragma unroll
        for (int kk = 0; kk < 4; ++kk) {
            bf16x8 bf = *(const bf16x8*)(kw + (jt * 16 + l15) * 136 + kk * 32 + quad * 8);
            accA[jt] = __builtin_amdgcn_mfma_f32_16x16x32_bf16(af[kk], bf, accA[jt], 0, 0, 0);
        }
    }
    // mask + Am + row sums -> denA
    {
        float rsum[4] = {0.f, 0.f, 0.f, 0.f};
        #pragma unroll
        for (int jt = 0; jt < 4; ++jt) {
            int j = jt * 16 + l15;
            #pragma unroll
            for (int r = 0; r < 4; ++r) {
                int i = it * 16 + quad * 4 + r;
                float val = (j <= i) ? accA[jt][r] : 0.f;
                Am[i * 72 + j] = f2bf(val);
                rsum[r] += val;
            }
        }
        #pragma unroll
        for (int off = 1; off < 16; off <<= 1) {
            rsum[0] += __shfl_xor(rsum[0], off);
            rsum[1] += __shfl_xor(rsum[1], off);
            rsum[2] += __shfl_xor(rsum[2], off);
            rsum[3] += __shfl_xor(rsum[3], off);
        }
        if (l15 == 0) {
            #pragma unroll
            for (int r = 0; r < 4; ++r) denA[it * 16 + quad * 4 + r] = rsum[r];
        }
    }
    // denI from af registers x psum: per-lane partial over 32 dd, reduce quads
    {
        float di = 0.f;
        #pragma unroll
        for (int kk = 0; kk < 4; ++kk) {
            f32x4 p0 = *(const f32x4*)(psum + kk * 32 + quad * 8);
            f32x4 p1 = *(const f32x4*)(psum + kk * 32 + quad * 8 + 4);
            di += bf2f((ushort)af[kk][0]) * p0.x + bf2f((ushort)af[kk][1]) * p0.y;
            di += bf2f((ushort)af[kk][2]) * p0.z + bf2f((ushort)af[kk][3]) * p0.w;
            di += bf2f((ushort)af[kk][4]) * p1.x + bf2f((ushort)af[kk][5]) * p1.y;
            di += bf2f((ushort)af[kk][6]) * p1.z + bf2f((ushort)af[kk][7]) * p1.w;
        }
        di += __shfl_xor(di, 16);
        di += __shfl_xor(di, 32);
        if (lane < 16) denI[it * 16 + l15] = di;
    }
    __syncthreads();

    // O = qw*P + Am*V
    f32x4 accO[2];
    #pragma unroll
    for (int mm = 0; mm < 2; ++mm) {
        accO[mm] = (f32x4){0.f, 0.f, 0.f, 0.f};
        #pragma unroll
        for (int kk = 0; kk < 4; ++kk) {
            bf16x8 bp = *(const bf16x8*)(Pt + (mm * 16 + l15) * 136 + kk * 32 + quad * 8);
            accO[mm] = __builtin_amdgcn_mfma_f32_16x16x32_bf16(af[kk], bp, accO[mm], 0, 0, 0);
        }
    }
    bf16x8 aA[2];
    #pragma unroll
    for (int kk = 0; kk < 2; ++kk)
        aA[kk] = *(const bf16x8*)(Am + (it * 16 + l15) * 72 + kk * 32 + quad * 8);
    #pragma unroll
    for (int mm = 0; mm < 2; ++mm)
        #pragma unroll
        for (int kk = 0; kk < 2; ++kk) {
            bf16x8 bv = *(const bf16x8*)(vT + (mm * 16 + l15) * 72 + kk * 32 + quad * 8);
            accO[mm] = __builtin_amdgcn_mfma_f32_16x16x32_bf16(aA[kk], bv, accO[mm], 0, 0, 0);
        }

    // normalize + repack into qw region (dead after af/denI), one uint4/thread
    ushort* Orep = (ushort*)(smem + OFF_QW);
    const int nb = b >> 3, hh = b & 7;
    #pragma unroll
    for (int r = 0; r < 4; ++r) {
        int i = it * 16 + quad * 4 + r;
        float inv = 1.0f / fmaxf(denA[i] + denI[i], EPSV);
        #pragma unroll
        for (int mm = 0; mm < 2; ++mm)
            Orep[i * 40 + mm * 16 + l15] = f2bf(accO[mm][r] * inv);
    }
    __syncthreads();
    {
        int rr = tid >> 2, f = (tid & 3) * 8;
        uint4 vv = *(const uint4*)(Orep + rr * 40 + f);
        *(uint4*)(attn216 + (size_t)((l0 + rr) * 2 + nb) * EMBED + hh * 64 + m0b + f) = vv;
    }
}

// ---------------------------------------------------------------------------
// Kernel C: out projection (bf16 x bf16).  32x64 tiles, grid 512 x 256.
// ---------------------------------------------------------------------------
__global__ __launch_bounds__(256) void kC_outproj(
    const ushort* __restrict__ A16, const ushort* __restrict__ W16,
    const float* __restrict__ bias, float* __restrict__ out,
    float4* __restrict__ probs4)
{
    __shared__ ushort Ab[32 * 72];
    __shared__ ushort Bb[64 * 72];
    const int bid = blockIdx.x;
    const int tid = threadIdx.x;
    {   // probs zero slice 2: 1,572,864 f4, nontemporal
        f32x4 z = {0.f, 0.f, 0.f, 0.f};
        size_t base = 2621440 + (size_t)bid * 3072 + tid;
        #pragma unroll
        for (int s = 0; s < 12; ++s)
            __builtin_nontemporal_store(z, (f32x4*)&probs4[base + s * 256]);
    }
    const int rt = bid >> 3, et = bid & 7;
    const int r0 = rt * 32, e0 = et * 64;
    const int w = tid >> 6, lane = tid & 63;
    const int quad = lane >> 4, l15 = lane & 15;
    const int it4 = w >> 1, jt0 = (w & 1) * 2;
    f32x4 acc4[2];
    acc4[0] = (f32x4){0.f, 0.f, 0.f, 0.f};
    acc4[1] = (f32x4){0.f, 0.f, 0.f, 0.f};

    for (int f0 = 0; f0 < EMBED; f0 += 64) {
        __syncthreads();
        {   // Ab: 32x64 bf16
            int rr = tid >> 3, ff = (tid & 7) * 8;
            *(uint4*)(Ab + rr * 72 + ff) = *(const uint4*)(A16 + (size_t)(r0 + rr) * EMBED + f0 + ff);
        }
        #pragma unroll
        for (int s = 0; s < 2; ++s) {   // Bb: 64x64 bf16
            int e = tid + s * 256;
            int rr = e >> 3, ff = (e & 7) * 8;
            *(uint4*)(Bb + rr * 72 + ff) = *(const uint4*)(W16 + (size_t)(e0 + rr) * EMBED + f0 + ff);
        }
        __syncthreads();
        bf16x8 af2[2];
        #pragma unroll
        for (int kk = 0; kk < 2; ++kk)
            af2[kk] = *(const bf16x8*)(Ab + (it4 * 16 + l15) * 72 + kk * 32 + quad * 8);
        #pragma unroll
        for (int jj = 0; jj < 2; ++jj) {
            int jt = jt0 + jj;
            #pragma unroll
            for (int kk = 0; kk < 2; ++kk) {
                bf16x8 bf = *(const bf16x8*)(Bb + (jt * 16 + l15) * 72 + kk * 32 + quad * 8);
                acc4[jj] = __builtin_amdgcn_mfma_f32_16x16x32_bf16(af2[kk], bf, acc4[jj], 0, 0, 0);
            }
        }
    }
    #pragma unroll
    for (int jj = 0; jj < 2; ++jj) {
        int e = e0 + (jt0 + jj) * 16 + l15;
        float be = bias[e];
        int h = e >> 6, m = e & 63;
        #pragma unroll
        for (int r = 0; r < 4; ++r) {
            int rr = r0 + it4 * 16 + quad * 4 + r;
            int t = rr >> 1, n = rr & 1;
            __builtin_nontemporal_store(acc4[jj][r] + be,
                &out[((size_t)(n * 8 + h) * TSEQ + t) * HIDV + m]);
        }
    }
}

// ---------------------------------------------------------------------------
extern "C" void kernel_launch(void* const* d_in, const int* in_sizes, int n_in,
                              void* d_out, int out_size, void* d_ws, size_t ws_size,
                              hipStream_t stream) {
    const float* q = (const float*)d_in[0];
    const float* k = (const float*)d_in[1];
    const float* v = (const float*)d_in[2];
    const float* W = (const float*)d_in[3];
    const float* bias = (const float*)d_in[4];
    float* out = (float*)d_out;
    float* ws = (float*)d_ws;

    ushort* S16 = (ushort*)ws;                        // 2,097,152 bf16 (4 MB)
    float* ksum_ws = ws + 1048576;                    // 32,768 fp32
    ushort* attn216 = (ushort*)(ws + 1081344);        // 1,048,576 bf16 (2 MB)
    ushort* W16 = (ushort*)(ws + 1605632);            // 262,144 bf16 (0.5 MB)
    float4* probs4 = (float4*)(out + CTX_FLOATS);

    kA_chunksum<<<dim3(512), dim3(256), 0, stream>>>(k, v, W, S16, ksum_ws, W16, probs4);
    kB_attn<<<dim3(512), dim3(256), 0, stream>>>(q, k, v, S16, ksum_ws, attn216, probs4);
    kC_outproj<<<dim3(512), dim3(256), 0, stream>>>(attn216, W16, bias, out, probs4);
}